// Round 1
// baseline (1409.552 us; speedup 1.0000x reference)
//
#include <hip/hip_runtime.h>
#include <math.h>

#define NH 16
#define HD 64
#define NB 2
#define LSEQ 2048
#define DM 1024
#define NLM 32

// out layout: y [4194304] | M_new [131072] | Z_new [2048]
#define OUT_M 4194304
#define OUT_Z 4325376

__device__ __forceinline__ float sigmoidf_(float x) { return 1.0f / (1.0f + __expf(-x)); }
// elu(x)+1
__device__ __forceinline__ float phif_(float x) { return x > 0.0f ? x + 1.0f : __expf(x); }

// ---------------------------------------------------------------------------
// C = A(M x 1024) @ W(1024 x 1024)^T.  MODE 0: write head-split (B,H,L,hd).
// MODE 1: plain row-major (M, 1024).
// BM=BN=64, BK=16, 256 threads, 4x4 per thread.
// ---------------------------------------------------------------------------
template <int MODE>
__global__ __launch_bounds__(256) void gemm_xwT(const float* __restrict__ A,
                                                const float* __restrict__ W,
                                                float* __restrict__ C) {
    __shared__ float As[16][68];
    __shared__ float Ws[16][68];
    const int tid = threadIdx.x;
    const int m0 = blockIdx.x * 64;
    const int n0 = blockIdx.y * 64;
    const int lr = tid >> 2;          // 0..63 row of tile to load
    const int lk = (tid & 3) << 2;    // k sub-offset 0,4,8,12
    const int ty = tid >> 4;          // 0..15
    const int tx = tid & 15;          // 0..15

    float acc[4][4] = {};
    const float* Arow = A + (size_t)(m0 + lr) * DM + lk;
    const float* Wrow = W + (size_t)(n0 + lr) * DM + lk;

    for (int k0 = 0; k0 < DM; k0 += 16) {
        float4 a4 = *reinterpret_cast<const float4*>(Arow + k0);
        float4 w4 = *reinterpret_cast<const float4*>(Wrow + k0);
        As[lk + 0][lr] = a4.x; As[lk + 1][lr] = a4.y;
        As[lk + 2][lr] = a4.z; As[lk + 3][lr] = a4.w;
        Ws[lk + 0][lr] = w4.x; Ws[lk + 1][lr] = w4.y;
        Ws[lk + 2][lr] = w4.z; Ws[lk + 3][lr] = w4.w;
        __syncthreads();
#pragma unroll
        for (int k = 0; k < 16; ++k) {
            float4 av = *reinterpret_cast<const float4*>(&As[k][ty << 2]);
            float4 wv = *reinterpret_cast<const float4*>(&Ws[k][tx << 2]);
            float aa[4] = {av.x, av.y, av.z, av.w};
            float ww[4] = {wv.x, wv.y, wv.z, wv.w};
#pragma unroll
            for (int i = 0; i < 4; ++i)
#pragma unroll
                for (int j = 0; j < 4; ++j)
                    acc[i][j] = fmaf(aa[i], ww[j], acc[i][j]);
        }
        __syncthreads();
    }

#pragma unroll
    for (int i = 0; i < 4; ++i) {
        const int m = m0 + (ty << 2) + i;
        const int n = n0 + (tx << 2);
        float4 o = make_float4(acc[i][0], acc[i][1], acc[i][2], acc[i][3]);
        if (MODE == 0) {
            const int b = m >> 11, l = m & (LSEQ - 1);
            const int h = n >> 6, d = n & 63;
            *reinterpret_cast<float4*>(&C[(((size_t)(b * NH + h)) * LSEQ + l) * HD + d]) = o;
        } else {
            *reinterpret_cast<float4*>(&C[(size_t)m * DM + n]) = o;
        }
    }
}

// ---------------------------------------------------------------------------
// Landmark memory update: one block per (b,h).
// lk = phi(chunk-mean of k_base), lv = chunk-mean of v, then
// M_new = M_old*decay + lk^T@lv ; Z_new = Z_old*decay + sum_m lk.
// ---------------------------------------------------------------------------
__global__ __launch_bounds__(256) void landmark_update(
    const float* __restrict__ kbase, const float* __restrict__ vbase,
    const float* __restrict__ M_old, const float* __restrict__ Z_old,
    const float* __restrict__ decay_p, float* __restrict__ out) {
    __shared__ float lk[NLM][HD];
    __shared__ float lv[NLM][HD];
    __shared__ float redk[4][HD];
    __shared__ float redv[4][HD];
    const int bh = blockIdx.x;
    const int tid = threadIdx.x;
    const int ls = tid >> 6;   // 0..3
    const int d = tid & 63;
    const float decay = sigmoidf_(decay_p[0]);
    const float* kb = kbase + (size_t)bh * LSEQ * HD;
    const float* vb = vbase + (size_t)bh * LSEQ * HD;

    for (int m = 0; m < NLM; ++m) {
        float sk = 0.f, sv = 0.f;
        for (int l = ls; l < 64; l += 4) {
            sk += kb[(size_t)(m * 64 + l) * HD + d];
            sv += vb[(size_t)(m * 64 + l) * HD + d];
        }
        redk[ls][d] = sk;
        redv[ls][d] = sv;
        __syncthreads();
        if (tid < 64) {
            lk[m][d] = (redk[0][d] + redk[1][d] + redk[2][d] + redk[3][d]) * (1.0f / 64.0f);
            lv[m][d] = (redv[0][d] + redv[1][d] + redv[2][d] + redv[3][d]) * (1.0f / 64.0f);
        }
        __syncthreads();
    }
    // phi on lk
    for (int p = 0; p < 8; ++p) {
        int idx = tid + 256 * p;   // 0..2047
        lk[idx >> 6][idx & 63] = phif_(lk[idx >> 6][idx & 63]);
    }
    __syncthreads();
    // M_new
    const size_t mo = (size_t)bh * HD * HD;
    for (int p = 0; p < 16; ++p) {
        int idx = tid + 256 * p;   // 0..4095, d = idx>>6, e = idx&63
        int dd = idx >> 6, e = idx & 63;
        float s = 0.f;
#pragma unroll
        for (int m = 0; m < NLM; ++m) s = fmaf(lk[m][dd], lv[m][e], s);
        out[OUT_M + mo + idx] = M_old[mo + idx] * decay + s;
    }
    // Z_new
    if (tid < 64) {
        float s = 0.f;
#pragma unroll
        for (int m = 0; m < NLM; ++m) s += lk[m][tid];
        out[OUT_Z + (size_t)bh * HD + tid] = Z_old[(size_t)bh * HD + tid] * decay + s;
    }
}

// ---------------------------------------------------------------------------
// Linear-attention memory read: ctx[b][l][h*64+e] = gate * (phiQ@M_old)/den.
// Block = (l-tile of 64 rows) x (b,h). 256 threads: 64 rows x 4 sub, 16 e each.
// ---------------------------------------------------------------------------
__global__ __launch_bounds__(256) void memory_read(
    const float* __restrict__ qbase, const float* __restrict__ M_old,
    const float* __restrict__ Z_old, const float* __restrict__ gate_p,
    float* __restrict__ ctx) {
    __shared__ float phiQ[64][68];
    __shared__ float Ms[64][64];
    __shared__ float Zs[64];
    const int l0 = blockIdx.x * 64;
    const int bh = blockIdx.y;
    const int b = bh >> 4, h = bh & 15;
    const int tid = threadIdx.x;
    const float gate = sigmoidf_(gate_p[0]);

    {
        const int r = tid >> 2, c0 = (tid & 3) << 4;
        const float* Mo = M_old + (size_t)bh * HD * HD + (size_t)r * HD + c0;
#pragma unroll
        for (int i = 0; i < 4; ++i)
            *reinterpret_cast<float4*>(&Ms[r][c0 + 4 * i]) =
                *reinterpret_cast<const float4*>(Mo + 4 * i);
        if (tid < 64) Zs[tid] = Z_old[(size_t)bh * HD + tid];
        const float* q = qbase + ((size_t)bh * LSEQ + l0 + r) * HD + c0;
#pragma unroll
        for (int i = 0; i < 4; ++i) {
            float4 q4 = *reinterpret_cast<const float4*>(q + 4 * i);
            phiQ[r][c0 + 4 * i + 0] = phif_(q4.x);
            phiQ[r][c0 + 4 * i + 1] = phif_(q4.y);
            phiQ[r][c0 + 4 * i + 2] = phif_(q4.z);
            phiQ[r][c0 + 4 * i + 3] = phif_(q4.w);
        }
    }
    __syncthreads();

    const int lr = tid >> 2, sub = tid & 3, e0 = sub << 4;
    float den = 0.f;
#pragma unroll
    for (int i = 0; i < 16; ++i) den = fmaf(phiQ[lr][e0 + i], Zs[e0 + i], den);
    den += __shfl_xor(den, 1);
    den += __shfl_xor(den, 2);
    den += 1e-6f;

    float acc[16] = {};
    for (int dd = 0; dd < 64; ++dd) {
        const float pq = phiQ[lr][dd];
#pragma unroll
        for (int i = 0; i < 16; ++i) acc[i] = fmaf(pq, Ms[dd][e0 + i], acc[i]);
    }
    const float g = gate / den;
    float* cp = ctx + ((size_t)b * LSEQ + l0 + lr) * DM + h * HD + e0;
#pragma unroll
    for (int i = 0; i < 4; ++i) {
        float4 o = make_float4(acc[4 * i] * g, acc[4 * i + 1] * g,
                               acc[4 * i + 2] * g, acc[4 * i + 3] * g);
        *reinterpret_cast<float4*>(cp + 4 * i) = o;
    }
}

// ---------------------------------------------------------------------------
// Causal flash attention with on-the-fly RoPE. Block = (q-tile 64) x (b,h).
// 256 threads: qi = tid>>2 (64 rows), sub = tid&3 (key-slice / 16-wide d-slice).
// ctx += local_out (ctx already holds gate*global_out).
// ---------------------------------------------------------------------------
__global__ __launch_bounds__(256) void flash_attn(
    const float* __restrict__ qbase, const float* __restrict__ kbase,
    const float* __restrict__ vbase, const float* __restrict__ fcos,
    const float* __restrict__ fsin, float* __restrict__ ctx) {
    __shared__ float Qs[64][68];
    __shared__ float Ks[32][68];
    __shared__ float Vs[32][68];
    __shared__ float Ps[64][33];
    const int qt = blockIdx.x;
    const int bh = blockIdx.y;
    const int b = bh >> 4, h = bh & 15;
    const int q0 = qt * 64;
    const int tid = threadIdx.x;

    // Q tile: rope + fold in 1/sqrt(hd)
    {
        const int r = tid >> 2, c0 = (tid & 3) << 4;
        const int lg = q0 + r;
        const float* q = qbase + ((size_t)bh * LSEQ + lg) * HD + c0;
        const float* cp = fcos + (size_t)lg * 32 + (c0 >> 1);
        const float* sp = fsin + (size_t)lg * 32 + (c0 >> 1);
#pragma unroll
        for (int i = 0; i < 4; ++i) {
            float4 q4 = *reinterpret_cast<const float4*>(q + 4 * i);
            float2 c2 = *reinterpret_cast<const float2*>(cp + 2 * i);
            float2 s2 = *reinterpret_cast<const float2*>(sp + 2 * i);
            const float sc = 0.125f;
            Qs[r][c0 + 4 * i + 0] = (q4.x * c2.x - q4.y * s2.x) * sc;
            Qs[r][c0 + 4 * i + 1] = (q4.x * s2.x + q4.y * c2.x) * sc;
            Qs[r][c0 + 4 * i + 2] = (q4.z * c2.y - q4.w * s2.y) * sc;
            Qs[r][c0 + 4 * i + 3] = (q4.z * s2.y + q4.w * c2.y) * sc;
        }
    }

    const int qi = tid >> 2, sub = tid & 3, e0 = sub << 4;
    const int qi_g = q0 + qi;
    float m_run = -INFINITY, l_run = 0.f;
    float acc[16] = {};
    const int ktmax = 2 * qt + 1;

    for (int kt = 0; kt <= ktmax; ++kt) {
        __syncthreads();  // prior-iter Ks/Vs/Ps reads done; Q visible on kt=0
        {
            const int r = tid >> 3, c0 = (tid & 7) << 3;
            const int lg = kt * 32 + r;
            const float* kr = kbase + ((size_t)bh * LSEQ + lg) * HD + c0;
            const float* vr = vbase + ((size_t)bh * LSEQ + lg) * HD + c0;
            const float* cp = fcos + (size_t)lg * 32 + (c0 >> 1);
            const float* sp = fsin + (size_t)lg * 32 + (c0 >> 1);
#pragma unroll
            for (int u = 0; u < 2; ++u) {
                float4 k4 = *reinterpret_cast<const float4*>(kr + 4 * u);
                float2 c2 = *reinterpret_cast<const float2*>(cp + 2 * u);
                float2 s2 = *reinterpret_cast<const float2*>(sp + 2 * u);
                Ks[r][c0 + 4 * u + 0] = k4.x * c2.x - k4.y * s2.x;
                Ks[r][c0 + 4 * u + 1] = k4.x * s2.x + k4.y * c2.x;
                Ks[r][c0 + 4 * u + 2] = k4.z * c2.y - k4.w * s2.y;
                Ks[r][c0 + 4 * u + 3] = k4.z * s2.y + k4.w * c2.y;
                *reinterpret_cast<float4*>(&Vs[r][c0 + 4 * u]) =
                    *reinterpret_cast<const float4*>(vr + 4 * u);
            }
        }
        __syncthreads();

        // scores: each thread 8 keys (kj = sub + 4j)
        float s[8];
#pragma unroll
        for (int j = 0; j < 8; ++j) s[j] = 0.f;
        for (int d4 = 0; d4 < 16; ++d4) {
            float4 q4 = *reinterpret_cast<const float4*>(&Qs[qi][4 * d4]);
#pragma unroll
            for (int j = 0; j < 8; ++j) {
                const int kj = sub + 4 * j;
                float4 k4 = *reinterpret_cast<const float4*>(&Ks[kj][4 * d4]);
                s[j] = fmaf(q4.x, k4.x,
                       fmaf(q4.y, k4.y, fmaf(q4.z, k4.z, fmaf(q4.w, k4.w, s[j]))));
            }
        }
        float tmax = -INFINITY;
#pragma unroll
        for (int j = 0; j < 8; ++j) {
            const int kg = kt * 32 + sub + 4 * j;
            if (kg > qi_g) s[j] = -INFINITY;  // causal mask
            tmax = fmaxf(tmax, s[j]);
        }
        tmax = fmaxf(tmax, __shfl_xor(tmax, 1));
        tmax = fmaxf(tmax, __shfl_xor(tmax, 2));
        const float m_new = fmaxf(m_run, tmax);  // finite after kt=0
        const float scale = __expf(m_run - m_new);
        float psum = 0.f;
        float p[8];
#pragma unroll
        for (int j = 0; j < 8; ++j) {
            p[j] = __expf(s[j] - m_new);
            psum += p[j];
        }
        psum += __shfl_xor(psum, 1);
        psum += __shfl_xor(psum, 2);
        l_run = l_run * scale + psum;
        m_run = m_new;
#pragma unroll
        for (int j = 0; j < 8; ++j) Ps[qi][sub + 4 * j] = p[j];
#pragma unroll
        for (int i = 0; i < 16; ++i) acc[i] *= scale;
        __syncthreads();

        // PV: acc[e0..e0+15] += P[qi][kj] * V[kj][e]
#pragma unroll 4
        for (int kj = 0; kj < 32; ++kj) {
            const float pv = Ps[qi][kj];
#pragma unroll
            for (int i4 = 0; i4 < 4; ++i4) {
                float4 v4 = *reinterpret_cast<const float4*>(&Vs[kj][e0 + 4 * i4]);
                acc[4 * i4 + 0] = fmaf(pv, v4.x, acc[4 * i4 + 0]);
                acc[4 * i4 + 1] = fmaf(pv, v4.y, acc[4 * i4 + 1]);
                acc[4 * i4 + 2] = fmaf(pv, v4.z, acc[4 * i4 + 2]);
                acc[4 * i4 + 3] = fmaf(pv, v4.w, acc[4 * i4 + 3]);
            }
        }
    }

    const float invl = 1.0f / l_run;
    float* cp = ctx + ((size_t)b * LSEQ + qi_g) * DM + h * HD + e0;
#pragma unroll
    for (int i4 = 0; i4 < 4; ++i4) {
        float4 c4 = *reinterpret_cast<float4*>(cp + 4 * i4);
        c4.x += acc[4 * i4 + 0] * invl;
        c4.y += acc[4 * i4 + 1] * invl;
        c4.z += acc[4 * i4 + 2] * invl;
        c4.w += acc[4 * i4 + 3] * invl;
        *reinterpret_cast<float4*>(cp + 4 * i4) = c4;
    }
}

// ---------------------------------------------------------------------------
extern "C" void kernel_launch(void* const* d_in, const int* in_sizes, int n_in,
                              void* d_out, int out_size, void* d_ws, size_t ws_size,
                              hipStream_t stream) {
    const float* x     = (const float*)d_in[0];
    const float* wq    = (const float*)d_in[1];
    const float* wk    = (const float*)d_in[2];
    const float* wv    = (const float*)d_in[3];
    const float* wo    = (const float*)d_in[4];
    const float* gate  = (const float*)d_in[5];
    const float* decay = (const float*)d_in[6];
    const float* fcos  = (const float*)d_in[7];
    const float* fsin  = (const float*)d_in[8];
    const float* M_old = (const float*)d_in[9];
    const float* Z_old = (const float*)d_in[10];
    float* out = (float*)d_out;

    // workspace: q | k | v | ctx, each B*H*L*hd = 4194304 floats (64 MB total)
    float* q   = (float*)d_ws;
    float* k   = q + 4194304;
    float* v   = k + 4194304;
    float* ctx = v + 4194304;

    dim3 bb(256);
    dim3 gg(64, 16);  // M/64 x N/64
    gemm_xwT<0><<<gg, bb, 0, stream>>>(x, wq, q);
    gemm_xwT<0><<<gg, bb, 0, stream>>>(x, wk, k);
    gemm_xwT<0><<<gg, bb, 0, stream>>>(x, wv, v);
    landmark_update<<<dim3(NB * NH), bb, 0, stream>>>(k, v, M_old, Z_old, decay, out);
    memory_read<<<dim3(LSEQ / 64, NB * NH), bb, 0, stream>>>(q, M_old, Z_old, gate, ctx);
    flash_attn<<<dim3(LSEQ / 64, NB * NH), bb, 0, stream>>>(q, k, v, fcos, fsin, ctx);
    gemm_xwT<1><<<gg, bb, 0, stream>>>(ctx, wo, out);
}

// Round 4
// 757.213 us; speedup vs baseline: 1.8615x; 1.8615x over previous
//
#include <hip/hip_runtime.h>
#include <math.h>

#define NH 16
#define HD 64
#define NB 2
#define LSEQ 2048
#define DM 1024
#define NLM 32

// out layout: y [4194304] | M_new [131072] | Z_new [2048]
#define OUT_M 4194304
#define OUT_Z 4325376

typedef unsigned short u16;
typedef short bf16x8 __attribute__((ext_vector_type(8)));
typedef float f32x16 __attribute__((ext_vector_type(16)));
typedef unsigned short u16x4 __attribute__((ext_vector_type(4)));

__device__ __forceinline__ float sigmoidf_(float x) { return 1.0f / (1.0f + __expf(-x)); }
__device__ __forceinline__ float phif_(float x) { return x > 0.0f ? x + 1.0f : __expf(x); }

__device__ __forceinline__ u16 f2b(float f) {
    union { float f; unsigned u; } v; v.f = f;
    unsigned r = v.u + 0x7FFFu + ((v.u >> 16) & 1u);
    return (u16)(r >> 16);
}
__device__ __forceinline__ float b2f(u16 b) {
    union { unsigned u; float f; } v; v.u = ((unsigned)b) << 16; return v.f;
}
__device__ __forceinline__ unsigned long long pack4(float a, float b, float c, float d) {
    return (unsigned long long)f2b(a) | ((unsigned long long)f2b(b) << 16) |
           ((unsigned long long)f2b(c) << 32) | ((unsigned long long)f2b(d) << 48);
}
__device__ __forceinline__ int cvtpkbf(float lo, float hi2) {
    int r;
    asm("v_cvt_pk_bf16_f32 %0, %1, %2" : "=v"(r) : "v"(lo), "v"(hi2));
    return r;
}

// ---------------------------------------------------------------------------
// C = A(M x 1024) @ W(1024 x 1024)^T, fp32 core.
// MODE 0: V   -> Cb bf16 head-split (B,H,L,hd)
// MODE 1: Y   -> Cf f32 row-major (M, 1024)
// MODE 2: Q   -> Cb = q_base bf16 head-split; Cr = q_rope bf16 (roped, *0.125)
// MODE 3: K   -> Cb = k_base bf16 head-split; Cr = k_rope bf16 (roped)
// ---------------------------------------------------------------------------
template <int MODE>
__global__ __launch_bounds__(256) void gemm_xwT(const float* __restrict__ A,
                                                const float* __restrict__ W,
                                                float* __restrict__ Cf,
                                                u16* __restrict__ Cb,
                                                u16* __restrict__ Cr,
                                                const float* __restrict__ fcos,
                                                const float* __restrict__ fsin) {
    __shared__ float As[16][68];
    __shared__ float Ws[16][68];
    const int tid = threadIdx.x;
    const int m0 = blockIdx.x * 64;
    const int n0 = blockIdx.y * 64;
    const int lr = tid >> 2;
    const int lk = (tid & 3) << 2;
    const int ty = tid >> 4;
    const int tx = tid & 15;

    float acc[4][4] = {};
    const float* Arow = A + (size_t)(m0 + lr) * DM + lk;
    const float* Wrow = W + (size_t)(n0 + lr) * DM + lk;

    for (int k0 = 0; k0 < DM; k0 += 16) {
        float4 a4 = *reinterpret_cast<const float4*>(Arow + k0);
        float4 w4 = *reinterpret_cast<const float4*>(Wrow + k0);
        As[lk + 0][lr] = a4.x; As[lk + 1][lr] = a4.y;
        As[lk + 2][lr] = a4.z; As[lk + 3][lr] = a4.w;
        Ws[lk + 0][lr] = w4.x; Ws[lk + 1][lr] = w4.y;
        Ws[lk + 2][lr] = w4.z; Ws[lk + 3][lr] = w4.w;
        __syncthreads();
#pragma unroll
        for (int k = 0; k < 16; ++k) {
            float4 av = *reinterpret_cast<const float4*>(&As[k][ty << 2]);
            float4 wv = *reinterpret_cast<const float4*>(&Ws[k][tx << 2]);
            float aa[4] = {av.x, av.y, av.z, av.w};
            float ww[4] = {wv.x, wv.y, wv.z, wv.w};
#pragma unroll
            for (int i = 0; i < 4; ++i)
#pragma unroll
                for (int j = 0; j < 4; ++j)
                    acc[i][j] = fmaf(aa[i], ww[j], acc[i][j]);
        }
        __syncthreads();
    }

#pragma unroll
    for (int i = 0; i < 4; ++i) {
        const int m = m0 + (ty << 2) + i;
        const int n = n0 + (tx << 2);
        if (MODE == 1) {
            float4 o = make_float4(acc[i][0], acc[i][1], acc[i][2], acc[i][3]);
            *reinterpret_cast<float4*>(&Cf[(size_t)m * DM + n]) = o;
        } else {
            const int b = m >> 11, l = m & (LSEQ - 1);
            const int h = n >> 6, d = n & 63;
            const size_t hs = (((size_t)(b * NH + h)) * LSEQ + l) * HD + d;
            *(unsigned long long*)(Cb + hs) = pack4(acc[i][0], acc[i][1], acc[i][2], acc[i][3]);
            if (MODE >= 2) {
                const float c0 = fcos[l * 32 + (d >> 1)], s0 = fsin[l * 32 + (d >> 1)];
                const float c1 = fcos[l * 32 + (d >> 1) + 1], s1 = fsin[l * 32 + (d >> 1) + 1];
                const float sc = (MODE == 2) ? 0.125f : 1.0f;
                const float o0 = (acc[i][0] * c0 - acc[i][1] * s0) * sc;
                const float o1 = (acc[i][0] * s0 + acc[i][1] * c0) * sc;
                const float o2 = (acc[i][2] * c1 - acc[i][3] * s1) * sc;
                const float o3 = (acc[i][2] * s1 + acc[i][3] * c1) * sc;
                *(unsigned long long*)(Cr + hs) = pack4(o0, o1, o2, o3);
            }
        }
    }
}

// ---------------------------------------------------------------------------
// Landmark memory update (bf16 k_base / v inputs)
// ---------------------------------------------------------------------------
__global__ __launch_bounds__(256) void landmark_update(
    const u16* __restrict__ kbase, const u16* __restrict__ vbase,
    const float* __restrict__ M_old, const float* __restrict__ Z_old,
    const float* __restrict__ decay_p, float* __restrict__ out) {
    __shared__ float lk[NLM][HD];
    __shared__ float lv[NLM][HD];
    __shared__ float redk[4][HD];
    __shared__ float redv[4][HD];
    const int bh = blockIdx.x;
    const int tid = threadIdx.x;
    const int ls = tid >> 6;
    const int d = tid & 63;
    const float decay = sigmoidf_(decay_p[0]);
    const u16* kb = kbase + (size_t)bh * LSEQ * HD;
    const u16* vb = vbase + (size_t)bh * LSEQ * HD;

    for (int m = 0; m < NLM; ++m) {
        float sk = 0.f, sv = 0.f;
        for (int l = ls; l < 64; l += 4) {
            sk += b2f(kb[(size_t)(m * 64 + l) * HD + d]);
            sv += b2f(vb[(size_t)(m * 64 + l) * HD + d]);
        }
        redk[ls][d] = sk;
        redv[ls][d] = sv;
        __syncthreads();
        if (tid < 64) {
            lk[m][d] = (redk[0][d] + redk[1][d] + redk[2][d] + redk[3][d]) * (1.0f / 64.0f);
            lv[m][d] = (redv[0][d] + redv[1][d] + redv[2][d] + redv[3][d]) * (1.0f / 64.0f);
        }
        __syncthreads();
    }
    for (int p = 0; p < 8; ++p) {
        int idx = tid + 256 * p;
        lk[idx >> 6][idx & 63] = phif_(lk[idx >> 6][idx & 63]);
    }
    __syncthreads();
    const size_t mo = (size_t)bh * HD * HD;
    for (int p = 0; p < 16; ++p) {
        int idx = tid + 256 * p;
        int dd = idx >> 6, e = idx & 63;
        float s = 0.f;
#pragma unroll
        for (int m = 0; m < NLM; ++m) s = fmaf(lk[m][dd], lv[m][e], s);
        out[OUT_M + mo + idx] = M_old[mo + idx] * decay + s;
    }
    if (tid < 64) {
        float s = 0.f;
#pragma unroll
        for (int m = 0; m < NLM; ++m) s += lk[m][tid];
        out[OUT_Z + (size_t)bh * HD + tid] = Z_old[(size_t)bh * HD + tid] * decay + s;
    }
}

// ---------------------------------------------------------------------------
// Linear-attention memory read (bf16 q_base input), writes ctx (f32, "=")
// ---------------------------------------------------------------------------
__global__ __launch_bounds__(256) void memory_read(
    const u16* __restrict__ qbase, const float* __restrict__ M_old,
    const float* __restrict__ Z_old, const float* __restrict__ gate_p,
    float* __restrict__ ctx) {
    __shared__ float phiQ[64][68];
    __shared__ float Ms[64][64];
    __shared__ float Zs[64];
    const int l0 = blockIdx.x * 64;
    const int bh = blockIdx.y;
    const int b = bh >> 4, h = bh & 15;
    const int tid = threadIdx.x;
    const float gate = sigmoidf_(gate_p[0]);

    {
        const int r = tid >> 2, c0 = (tid & 3) << 4;
        const float* Mo = M_old + (size_t)bh * HD * HD + (size_t)r * HD + c0;
#pragma unroll
        for (int i = 0; i < 4; ++i)
            *reinterpret_cast<float4*>(&Ms[r][c0 + 4 * i]) =
                *reinterpret_cast<const float4*>(Mo + 4 * i);
        if (tid < 64) Zs[tid] = Z_old[(size_t)bh * HD + tid];
        const u16* q = qbase + ((size_t)bh * LSEQ + l0 + r) * HD + c0;
#pragma unroll
        for (int i = 0; i < 4; ++i) {
            u16x4 q4 = *(const u16x4*)(q + 4 * i);
            phiQ[r][c0 + 4 * i + 0] = phif_(b2f(q4[0]));
            phiQ[r][c0 + 4 * i + 1] = phif_(b2f(q4[1]));
            phiQ[r][c0 + 4 * i + 2] = phif_(b2f(q4[2]));
            phiQ[r][c0 + 4 * i + 3] = phif_(b2f(q4[3]));
        }
    }
    __syncthreads();

    const int lr = tid >> 2, sub = tid & 3, e0 = sub << 4;
    float den = 0.f;
#pragma unroll
    for (int i = 0; i < 16; ++i) den = fmaf(phiQ[lr][e0 + i], Zs[e0 + i], den);
    den += __shfl_xor(den, 1);
    den += __shfl_xor(den, 2);
    den += 1e-6f;

    float acc[16] = {};
    for (int dd = 0; dd < 64; ++dd) {
        const float pq = phiQ[lr][dd];
#pragma unroll
        for (int i = 0; i < 16; ++i) acc[i] = fmaf(pq, Ms[dd][e0 + i], acc[i]);
    }
    const float g = gate / den;
    float* cp = ctx + ((size_t)b * LSEQ + l0 + lr) * DM + h * HD + e0;
#pragma unroll
    for (int i = 0; i < 4; ++i) {
        float4 o = make_float4(acc[4 * i] * g, acc[4 * i + 1] * g,
                               acc[4 * i + 2] * g, acc[4 * i + 3] * g);
        *reinterpret_cast<float4*>(cp + 4 * i) = o;
    }
}

// ---------------------------------------------------------------------------
// MFMA flash attention (bf16), swapped-operand structure.
// Block: 128 q-rows x (b,h); 4 waves, 32 q-rows each. KVBLK=32.
// QK^T: S^T[key][q] = mfma(K, Q)  (q = lane&31 -> softmax lane-local)
// PV:   O^T[d][q]   = mfma(V^T, P^T)  (rescale lane-local)
// K LDS: row-major XOR-swizzled.
// V LDS: EXPLICIT V^T [64 d][32 keys], chunk-swizzled by (d>>3)&3; A-frags
//        read with plain ds_read_b128 (replaces ds_read_b64_tr_b16 path).
// ctx += O (ctx pre-filled by memory_read).
// ---------------------------------------------------------------------------
__global__ __launch_bounds__(256) void flash_mfma(
    const u16* __restrict__ qr, const u16* __restrict__ kr,
    const u16* __restrict__ vv, float* __restrict__ ctx) {
    __shared__ int4 smem4[2048];   // 32 KB: Q[0,16K) | K0 16K | K1 20K | Vt0 24K | Vt1 28K
    char* lds = (char*)smem4;

    const int bx = blockIdx.x;
    const int bh = blockIdx.y;
    const int q0 = bx * 128;
    const int tid = threadIdx.x;
    const int w = tid >> 6;
    const int lane = tid & 63;
    const int hi = lane >> 5;
    const int l31 = lane & 31;
    const int qw0 = q0 + w * 32;
    const int diag = bx * 4 + w;
    const int nt = bx * 4 + 4;
    const size_t base_bh = (size_t)bh * (LSEQ * HD);

    // ---- stage Q (128x64 bf16, XOR-swizzled rows) ----
#pragma unroll
    for (int i = 0; i < 4; ++i) {
        int u = tid + 256 * i;
        int row = u >> 3, c = u & 7;
        int4 val = *(const int4*)(qr + base_bh + (size_t)(q0 + row) * HD + c * 8);
        *(int4*)(lds + row * 128 + ((c ^ (row & 7)) * 16)) = val;
    }

    // staging maps
    const int st_row = tid >> 3, st_c = tid & 7;
    const int sk_off = st_row * 128 + ((st_c ^ (st_row & 7)) * 16);
    // V^T staging: thread holds V[sv_k][sv_d0..sv_d0+7]; scatters to
    // Vt byte addr (d)*64 + ((k>>3)^((d>>3)&3))*16 + (k&7)*2  (d>>3 const per thread)
    const int sv_k = tid >> 3, sv_d0 = (tid & 7) << 3;
    const int sv_kpos = (((sv_k >> 3) ^ ((sv_d0 >> 3) & 3)) * 16) + (sv_k & 7) * 2;
    const int sv_base = sv_d0 * 64 + sv_kpos;

    int4 RAk = *(const int4*)(kr + base_bh + (size_t)st_row * HD + st_c * 8);
    int4 RAv = *(const int4*)(vv + base_bh + (size_t)sv_k * HD + sv_d0);
    __syncthreads();   // Q visible

    // Q fragments (held in registers for all tiles)
    bf16x8 qf[4];
    {
        const char* qrow = lds + ((w << 5) + l31) * 128;
        const int sw = l31 & 7;
#pragma unroll
        for (int ks = 0; ks < 4; ++ks) {
            int c = 2 * ks + hi;
            qf[ks] = *(const bf16x8*)(qrow + ((c ^ sw) * 16));
        }
    }
    // tile0 -> buf0 ; prefetch tile1
    *(int4*)(lds + 16384 + sk_off) = RAk;
    {
        union { int4 q; u16 h[8]; } uv; uv.q = RAv;
        char* vd = lds + 24576 + sv_base;
#pragma unroll
        for (int e = 0; e < 8; ++e) *(u16*)(vd + e * 64) = uv.h[e];
    }
    int4 RBk = *(const int4*)(kr + base_bh + (size_t)(32 + st_row) * HD + st_c * 8);
    int4 RBv = *(const int4*)(vv + base_bh + (size_t)(32 + sv_k) * HD + sv_d0);
    __syncthreads();   // buf0 visible

    f32x16 accO[2];
#pragma unroll
    for (int mf = 0; mf < 2; ++mf)
#pragma unroll
        for (int i = 0; i < 16; ++i) accO[mf][i] = 0.f;
    float m_run = -INFINITY, l_run = 0.f;

    const int swK = l31 & 7;
    const int rowK = l31 * 128;
    const int vr0 = l31 * 64;              // V^T row offset within mf-block
    const int vsw = (l31 >> 3) & 3;        // V^T chunk swizzle for this lane

    auto compute_tile = [&](int kt, int kbase_off, int vbase_off) {
        // --- QK^T: S^T = sum_ks mfma(Kfrag, Qfrag) ---
        f32x16 st;
#pragma unroll
        for (int i = 0; i < 16; ++i) st[i] = 0.f;
        const char* kb = lds + kbase_off;
#pragma unroll
        for (int ks = 0; ks < 4; ++ks) {
            int c = 2 * ks + hi;
            bf16x8 kf = *(const bf16x8*)(kb + rowK + ((c ^ swK) * 16));
            st = __builtin_amdgcn_mfma_f32_32x32x16_bf16(kf, qf[ks], st, 0, 0, 0);
        }
        // --- V^T A-frags: plain b128 reads (chunk c = kb2*2 + hi) ---
        const char* vb = lds + vbase_off;
        bf16x8 va00 = *(const bf16x8*)(vb + vr0 + (((0 + hi) ^ vsw) * 16));          // kb2=0, mf=0
        bf16x8 va01 = *(const bf16x8*)(vb + 2048 + vr0 + (((0 + hi) ^ vsw) * 16));   // kb2=0, mf=1
        bf16x8 va10 = *(const bf16x8*)(vb + vr0 + (((2 + hi) ^ vsw) * 16));          // kb2=1, mf=0
        bf16x8 va11 = *(const bf16x8*)(vb + 2048 + vr0 + (((2 + hi) ^ vsw) * 16));   // kb2=1, mf=1

        // --- softmax (lane-local for q = lane&31) ---
        float s[16];
#pragma unroll
        for (int r = 0; r < 16; ++r) s[r] = st[r];
        if (kt == diag) {
            const int qg = qw0 + l31;
#pragma unroll
            for (int r = 0; r < 16; ++r) {
                int keyg = kt * 32 + (r & 3) + 8 * (r >> 2) + 4 * hi;
                if (keyg > qg) s[r] = -INFINITY;
            }
        }
        float t8[8];
#pragma unroll
        for (int r = 0; r < 8; ++r) t8[r] = fmaxf(s[r], s[r + 8]);
        float t4m[4];
#pragma unroll
        for (int r = 0; r < 4; ++r) t4m[r] = fmaxf(t8[r], t8[r + 4]);
        float mm = fmaxf(fmaxf(t4m[0], t4m[1]), fmaxf(t4m[2], t4m[3]));
        mm = fmaxf(mm, __shfl_xor(mm, 32));
        const float m_new = fmaxf(m_run, mm);
        const float sc = __expf(m_run - m_new);
        float p[16];
#pragma unroll
        for (int r = 0; r < 16; ++r) { p[r] = __expf(s[r] - m_new); }
        float a8[8];
#pragma unroll
        for (int r = 0; r < 8; ++r) a8[r] = p[r] + p[r + 8];
        float a4s[4];
#pragma unroll
        for (int r = 0; r < 4; ++r) a4s[r] = a8[r] + a8[r + 4];
        float ss = (a4s[0] + a4s[1]) + (a4s[2] + a4s[3]);
        ss += __shfl_xor(ss, 32);
        l_run = l_run * sc + ss;
        m_run = m_new;
#pragma unroll
        for (int mf = 0; mf < 2; ++mf)
#pragma unroll
            for (int i = 0; i < 16; ++i) accO[mf][i] *= sc;

        // --- P -> B-frag (bf16): cvt_pk + cross-half shuffle + select ---
        int pk[8];
#pragma unroll
        for (int i = 0; i < 8; ++i) pk[i] = cvtpkbf(p[2 * i], p[2 * i + 1]);
        int xp0 = __shfl_xor(pk[0], 32);
        int xp1 = __shfl_xor(pk[1], 32);
        int xp2 = __shfl_xor(pk[2], 32);
        int xp3 = __shfl_xor(pk[3], 32);
        int xp4 = __shfl_xor(pk[4], 32);
        int xp5 = __shfl_xor(pk[5], 32);
        int xp6 = __shfl_xor(pk[6], 32);
        int xp7 = __shfl_xor(pk[7], 32);
        const bool hib = (hi != 0);
        union { int i[4]; bf16x8 v; } pu0, pu1;
        pu0.i[0] = hib ? xp2 : pk[0];
        pu0.i[1] = hib ? xp3 : pk[1];
        pu0.i[2] = hib ? pk[2] : xp0;
        pu0.i[3] = hib ? pk[3] : xp1;
        pu1.i[0] = hib ? xp6 : pk[4];
        pu1.i[1] = hib ? xp7 : pk[5];
        pu1.i[2] = hib ? pk[6] : xp4;
        pu1.i[3] = hib ? pk[7] : xp5;

        // --- PV MFMAs ---
        accO[0] = __builtin_amdgcn_mfma_f32_32x32x16_bf16(va00, pu0.v, accO[0], 0, 0, 0);
        accO[1] = __builtin_amdgcn_mfma_f32_32x32x16_bf16(va01, pu0.v, accO[1], 0, 0, 0);
        accO[0] = __builtin_amdgcn_mfma_f32_32x32x16_bf16(va10, pu1.v, accO[0], 0, 0, 0);
        accO[1] = __builtin_amdgcn_mfma_f32_32x32x16_bf16(va11, pu1.v, accO[1], 0, 0, 0);
    };

    for (int kt = 0; kt < nt; kt += 2) {
        // even: write tile kt+1 -> buf1, prefetch kt+2, compute buf0
        *(int4*)(lds + 16384 + 4096 + sk_off) = RBk;
        {
            union { int4 q; u16 h[8]; } uv; uv.q = RBv;
            char* vd = lds + 24576 + 4096 + sv_base;
#pragma unroll
            for (int e = 0; e < 8; ++e) *(u16*)(vd + e * 64) = uv.h[e];
        }
        if (kt + 2 < nt) {
            RAk = *(const int4*)(kr + base_bh + (size_t)((kt + 2) * 32 + st_row) * HD + st_c * 8);
            RAv = *(const int4*)(vv + base_bh + (size_t)((kt + 2) * 32 + sv_k) * HD + sv_d0);
        }
        if (kt <= diag) compute_tile(kt, 16384, 24576);
        __syncthreads();
        // odd: write tile kt+2 -> buf0, prefetch kt+3, compute buf1
        if (kt + 2 < nt) {
            *(int4*)(lds + 16384 + sk_off) = RAk;
            union { int4 q; u16 h[8]; } uv; uv.q = RAv;
            char* vd = lds + 24576 + sv_base;
#pragma unroll
            for (int e = 0; e < 8; ++e) *(u16*)(vd + e * 64) = uv.h[e];
        }
        if (kt + 3 < nt) {
            RBk = *(const int4*)(kr + base_bh + (size_t)((kt + 3) * 32 + st_row) * HD + st_c * 8);
            RBv = *(const int4*)(vv + base_bh + (size_t)((kt + 3) * 32 + sv_k) * HD + sv_d0);
        }
        if (kt + 1 <= diag) compute_tile(kt + 1, 16384 + 4096, 24576 + 4096);
        __syncthreads();
    }

    // ---- epilogue: ctx += O (row q = qw0 + l31 fixed per lane) ----
    const float invl = 1.0f / l_run;
    const int qg = qw0 + l31;
    float* cbase = ctx + ((size_t)(bh >> 4) * LSEQ + qg) * DM + (bh & 15) * HD;
#pragma unroll
    for (int mf = 0; mf < 2; ++mf) {
#pragma unroll
        for (int g = 0; g < 4; ++g) {
            const int d4 = mf * 32 + 8 * g + 4 * hi;
            float4 c4 = *(float4*)(cbase + d4);
            c4.x += accO[mf][g * 4 + 0] * invl;
            c4.y += accO[mf][g * 4 + 1] * invl;
            c4.z += accO[mf][g * 4 + 2] * invl;
            c4.w += accO[mf][g * 4 + 3] * invl;
            *(float4*)(cbase + d4) = c4;
        }
    }
}

// ---------------------------------------------------------------------------
extern "C" void kernel_launch(void* const* d_in, const int* in_sizes, int n_in,
                              void* d_out, int out_size, void* d_ws, size_t ws_size,
                              hipStream_t stream) {
    const float* x     = (const float*)d_in[0];
    const float* wq    = (const float*)d_in[1];
    const float* wk    = (const float*)d_in[2];
    const float* wv    = (const float*)d_in[3];
    const float* wo    = (const float*)d_in[4];
    const float* gate  = (const float*)d_in[5];
    const float* decay = (const float*)d_in[6];
    const float* fcos  = (const float*)d_in[7];
    const float* fsin  = (const float*)d_in[8];
    const float* M_old = (const float*)d_in[9];
    const float* Z_old = (const float*)d_in[10];
    float* out = (float*)d_out;

    // ws: q_rope | q_base | k_rope | k_base | v (bf16, 8MB each) | ctx (f32 16MB)
    u16* q_rope = (u16*)d_ws;
    u16* q_base = q_rope + 4194304;
    u16* k_rope = q_base + 4194304;
    u16* k_base = k_rope + 4194304;
    u16* v      = k_base + 4194304;
    float* ctx  = (float*)(v + 4194304);

    dim3 bb(256);
    dim3 gg(64, 16);
    gemm_xwT<2><<<gg, bb, 0, stream>>>(x, wq, nullptr, q_base, q_rope, fcos, fsin);
    gemm_xwT<3><<<gg, bb, 0, stream>>>(x, wk, nullptr, k_base, k_rope, fcos, fsin);
    gemm_xwT<0><<<gg, bb, 0, stream>>>(x, wv, nullptr, v, nullptr, nullptr, nullptr);
    landmark_update<<<dim3(NB * NH), bb, 0, stream>>>(k_base, v, M_old, Z_old, decay, out);
    memory_read<<<dim3(LSEQ / 64, NB * NH), bb, 0, stream>>>(q_base, M_old, Z_old, gate, ctx);
    flash_mfma<<<dim3(LSEQ / 128, NB * NH), bb, 0, stream>>>(q_rope, k_rope, v, ctx);
    gemm_xwT<1><<<gg, bb, 0, stream>>>(ctx, wo, out, nullptr, nullptr, nullptr, nullptr);
}

// Round 5
// 221.808 us; speedup vs baseline: 6.3548x; 3.4138x over previous
//
#include <hip/hip_runtime.h>
#include <math.h>

#define NH 16
#define HD 64
#define NB 2
#define LSEQ 2048
#define DM 1024
#define NLM 32

// out layout: y [4194304] | M_new [131072] | Z_new [2048]
#define OUT_M 4194304
#define OUT_Z 4325376

typedef unsigned short u16;
typedef short bf16x8 __attribute__((ext_vector_type(8)));
typedef float f32x16 __attribute__((ext_vector_type(16)));
typedef unsigned short u16x4 __attribute__((ext_vector_type(4)));

__device__ __forceinline__ float sigmoidf_(float x) { return 1.0f / (1.0f + __expf(-x)); }
__device__ __forceinline__ float phif_(float x) { return x > 0.0f ? x + 1.0f : __expf(x); }

__device__ __forceinline__ u16 f2b(float f) {
    union { float f; unsigned u; } v; v.f = f;
    unsigned r = v.u + 0x7FFFu + ((v.u >> 16) & 1u);
    return (u16)(r >> 16);
}
__device__ __forceinline__ float b2f(u16 b) {
    union { unsigned u; float f; } v; v.u = ((unsigned)b) << 16; return v.f;
}
__device__ __forceinline__ int cvtpkbf(float lo, float hi2) {
    int r;
    asm("v_cvt_pk_bf16_f32 %0, %1, %2" : "=v"(r) : "v"(lo), "v"(hi2));
    return r;
}

// ---------------------------------------------------------------------------
// f32 -> bf16 elementwise convert (n multiple of 8)
// ---------------------------------------------------------------------------
__global__ __launch_bounds__(256) void cvt_bf16(const float* __restrict__ src,
                                                u16* __restrict__ dst, int n) {
    int i = (blockIdx.x * 256 + threadIdx.x) * 8;
    if (i >= n) return;
    float4 a = *(const float4*)(src + i);
    float4 b = *(const float4*)(src + i + 4);
    u16 o[8] = {f2b(a.x), f2b(a.y), f2b(a.z), f2b(a.w),
                f2b(b.x), f2b(b.y), f2b(b.z), f2b(b.w)};
    *(int4*)(dst + i) = *(int4*)o;
}

// ---------------------------------------------------------------------------
// MFMA GEMM: C[M=4096, N=1024] = A @ W^T   (A, W bf16; 32x32x16 MFMA)
// Tile 128x64, BK=64, 4 waves as 2x2 (wave region 64x32, 2 M-frags).
// MODE 0: V   -> Cb bf16 head-split (B,H,L,hd)
// MODE 1: Y   -> Cf f32 row-major
// MODE 2: Q   -> Cb = q_base bf16 head-split; Cr = q_rope (*0.125)
// MODE 3: K   -> Cb = k_base bf16 head-split; Cr = k_rope
// ---------------------------------------------------------------------------
template <int MODE>
__global__ __launch_bounds__(256) void gemm_mfma(const u16* __restrict__ A,
                                                 const u16* __restrict__ W,
                                                 float* __restrict__ Cf,
                                                 u16* __restrict__ Cb,
                                                 u16* __restrict__ Cr,
                                                 const float* __restrict__ fcos,
                                                 const float* __restrict__ fsin) {
    __shared__ u16 As[128 * 72];   // 128 rows x 64 k, padded to 72 u16 (144B)
    __shared__ u16 Ws[64 * 72];
    const int tid = threadIdx.x;
    const int m0 = blockIdx.x * 128;
    const int n0 = blockIdx.y * 64;
    const int w = tid >> 6;
    const int lane = tid & 63;
    const int l31 = lane & 31;
    const int khalf = lane >> 5;           // 0/1 -> k offset 0/8
    const int wr0 = (w >> 1) * 64;         // wave rows within tile
    const int wc0 = (w & 1) * 32;          // wave cols within tile

    const u16* Ag = A + (size_t)m0 * DM;
    const u16* Wg = W + (size_t)n0 * DM;

    f32x16 acc[2];
#pragma unroll
    for (int fm = 0; fm < 2; ++fm)
#pragma unroll
        for (int i = 0; i < 16; ++i) acc[fm][i] = 0.f;

    for (int k0 = 0; k0 < DM; k0 += 64) {
        __syncthreads();
#pragma unroll
        for (int i = 0; i < 4; ++i) {
            int g = tid + 256 * i;
            int row = g >> 3, c = g & 7;
            *(int4*)(As + row * 72 + c * 8) =
                *(const int4*)(Ag + (size_t)row * DM + k0 + c * 8);
        }
#pragma unroll
        for (int i = 0; i < 2; ++i) {
            int g = tid + 256 * i;
            int row = g >> 3, c = g & 7;
            *(int4*)(Ws + row * 72 + c * 8) =
                *(const int4*)(Wg + (size_t)row * DM + k0 + c * 8);
        }
        __syncthreads();
#pragma unroll
        for (int ko = 0; ko < 4; ++ko) {
            bf16x8 bfr = *(const bf16x8*)(Ws + (wc0 + l31) * 72 + ko * 16 + khalf * 8);
            bf16x8 af0 = *(const bf16x8*)(As + (wr0 + l31) * 72 + ko * 16 + khalf * 8);
            bf16x8 af1 = *(const bf16x8*)(As + (wr0 + 32 + l31) * 72 + ko * 16 + khalf * 8);
            acc[0] = __builtin_amdgcn_mfma_f32_32x32x16_bf16(af0, bfr, acc[0], 0, 0, 0);
            acc[1] = __builtin_amdgcn_mfma_f32_32x32x16_bf16(af1, bfr, acc[1], 0, 0, 0);
        }
    }

    // epilogue: D map (verified): col = l31, row = (reg&3)+8*(reg>>2)+4*khalf
    const int n = n0 + wc0 + l31;
#pragma unroll
    for (int fm = 0; fm < 2; ++fm) {
#pragma unroll
        for (int reg = 0; reg < 16; ++reg) {
            const int m = m0 + wr0 + fm * 32 + (reg & 3) + 8 * (reg >> 2) + 4 * khalf;
            const float val = acc[fm][reg];
            if (MODE == 1) {
                Cf[(size_t)m * DM + n] = val;
            } else {
                const int b = m >> 11, l = m & (LSEQ - 1);
                const int h = n >> 6, d = n & 63;
                const size_t hs = (((size_t)(b * NH + h)) * LSEQ + l) * HD + d;
                Cb[hs] = f2b(val);
                if (MODE >= 2) {
                    const float p = __shfl_xor(val, 1);  // partner d^1, same m
                    const float c = fcos[l * 32 + (d >> 1)];
                    const float s = fsin[l * 32 + (d >> 1)];
                    float o = (d & 1) ? (p * s + val * c) : (val * c - p * s);
                    if (MODE == 2) o *= 0.125f;
                    Cr[hs] = f2b(o);
                }
            }
        }
    }
}

// ---------------------------------------------------------------------------
// Landmarks: one block per (b,h,m) chunk -> phi(k-mean), v-mean  (f32 out)
// ---------------------------------------------------------------------------
__global__ __launch_bounds__(256) void landmarks(
    const u16* __restrict__ kbase, const u16* __restrict__ vbase,
    float* __restrict__ lkq, float* __restrict__ lvq) {
    __shared__ float redk[4][HD];
    __shared__ float redv[4][HD];
    const int bh = blockIdx.x >> 5;
    const int m = blockIdx.x & 31;
    const int tid = threadIdx.x;
    const int ls = tid >> 6;
    const int d = tid & 63;
    const u16* kb = kbase + ((size_t)bh * LSEQ + m * 64) * HD;
    const u16* vb = vbase + ((size_t)bh * LSEQ + m * 64) * HD;
    float sk = 0.f, sv = 0.f;
    for (int l = ls; l < 64; l += 4) {
        sk += b2f(kb[(size_t)l * HD + d]);
        sv += b2f(vb[(size_t)l * HD + d]);
    }
    redk[ls][d] = sk;
    redv[ls][d] = sv;
    __syncthreads();
    if (tid < 64) {
        float mk = (redk[0][d] + redk[1][d] + redk[2][d] + redk[3][d]) * (1.0f / 64.0f);
        float mv = (redv[0][d] + redv[1][d] + redv[2][d] + redv[3][d]) * (1.0f / 64.0f);
        lkq[((size_t)bh * NLM + m) * HD + d] = phif_(mk);
        lvq[((size_t)bh * NLM + m) * HD + d] = mv;
    }
}

// ---------------------------------------------------------------------------
// Memory update: M_new = M_old*decay + lk^T@lv ; Z_new = Z_old*decay + sum lk
// ---------------------------------------------------------------------------
__global__ __launch_bounds__(256) void mem_update(
    const float* __restrict__ lkq, const float* __restrict__ lvq,
    const float* __restrict__ M_old, const float* __restrict__ Z_old,
    const float* __restrict__ decay_p, float* __restrict__ out) {
    __shared__ float lk[NLM][HD];
    __shared__ float lv[NLM][HD];
    const int bh = blockIdx.x;
    const int tid = threadIdx.x;
    const float decay = sigmoidf_(decay_p[0]);
#pragma unroll
    for (int i = 0; i < 8; ++i) {
        int idx = tid + 256 * i;
        lk[idx >> 6][idx & 63] = lkq[(size_t)bh * (NLM * HD) + idx];
        lv[idx >> 6][idx & 63] = lvq[(size_t)bh * (NLM * HD) + idx];
    }
    __syncthreads();
    const size_t mo = (size_t)bh * HD * HD;
#pragma unroll
    for (int p = 0; p < 16; ++p) {
        int idx = tid + 256 * p;
        int dd = idx >> 6, e = idx & 63;
        float s = 0.f;
#pragma unroll
        for (int m = 0; m < NLM; ++m) s = fmaf(lk[m][dd], lv[m][e], s);
        out[OUT_M + mo + idx] = M_old[mo + idx] * decay + s;
    }
    if (tid < 64) {
        float s = 0.f;
#pragma unroll
        for (int m = 0; m < NLM; ++m) s += lk[m][tid];
        out[OUT_Z + (size_t)bh * HD + tid] = Z_old[(size_t)bh * HD + tid] * decay + s;
    }
}

// ---------------------------------------------------------------------------
// Linear-attention memory read (bf16 q_base input), writes ctx (f32, "=")
// ---------------------------------------------------------------------------
__global__ __launch_bounds__(256) void memory_read(
    const u16* __restrict__ qbase, const float* __restrict__ M_old,
    const float* __restrict__ Z_old, const float* __restrict__ gate_p,
    float* __restrict__ ctx) {
    __shared__ float phiQ[64][68];
    __shared__ float Ms[64][64];
    __shared__ float Zs[64];
    const int l0 = blockIdx.x * 64;
    const int bh = blockIdx.y;
    const int b = bh >> 4, h = bh & 15;
    const int tid = threadIdx.x;
    const float gate = sigmoidf_(gate_p[0]);

    {
        const int r = tid >> 2, c0 = (tid & 3) << 4;
        const float* Mo = M_old + (size_t)bh * HD * HD + (size_t)r * HD + c0;
#pragma unroll
        for (int i = 0; i < 4; ++i)
            *reinterpret_cast<float4*>(&Ms[r][c0 + 4 * i]) =
                *reinterpret_cast<const float4*>(Mo + 4 * i);
        if (tid < 64) Zs[tid] = Z_old[(size_t)bh * HD + tid];
        const u16* q = qbase + ((size_t)bh * LSEQ + l0 + r) * HD + c0;
#pragma unroll
        for (int i = 0; i < 4; ++i) {
            u16x4 q4 = *(const u16x4*)(q + 4 * i);
            phiQ[r][c0 + 4 * i + 0] = phif_(b2f(q4[0]));
            phiQ[r][c0 + 4 * i + 1] = phif_(b2f(q4[1]));
            phiQ[r][c0 + 4 * i + 2] = phif_(b2f(q4[2]));
            phiQ[r][c0 + 4 * i + 3] = phif_(b2f(q4[3]));
        }
    }
    __syncthreads();

    const int lr = tid >> 2, sub = tid & 3, e0 = sub << 4;
    float den = 0.f;
#pragma unroll
    for (int i = 0; i < 16; ++i) den = fmaf(phiQ[lr][e0 + i], Zs[e0 + i], den);
    den += __shfl_xor(den, 1);
    den += __shfl_xor(den, 2);
    den += 1e-6f;

    float acc[16] = {};
    for (int dd = 0; dd < 64; ++dd) {
        const float pq = phiQ[lr][dd];
#pragma unroll
        for (int i = 0; i < 16; ++i) acc[i] = fmaf(pq, Ms[dd][e0 + i], acc[i]);
    }
    const float g = gate / den;
    float* cp = ctx + ((size_t)b * LSEQ + l0 + lr) * DM + h * HD + e0;
#pragma unroll
    for (int i = 0; i < 4; ++i) {
        float4 o = make_float4(acc[4 * i] * g, acc[4 * i + 1] * g,
                               acc[4 * i + 2] * g, acc[4 * i + 3] * g);
        *reinterpret_cast<float4*>(cp + 4 * i) = o;
    }
}

// ---------------------------------------------------------------------------
// MFMA flash attention (bf16), swapped-operand structure. (unchanged, verified)
// ---------------------------------------------------------------------------
__global__ __launch_bounds__(256) void flash_mfma(
    const u16* __restrict__ qr, const u16* __restrict__ kr,
    const u16* __restrict__ vv, float* __restrict__ ctx) {
    __shared__ int4 smem4[2048];   // 32 KB: Q[0,16K) | K0 16K | K1 20K | Vt0 24K | Vt1 28K
    char* lds = (char*)smem4;

    const int bx = blockIdx.x;
    const int bh = blockIdx.y;
    const int q0 = bx * 128;
    const int tid = threadIdx.x;
    const int w = tid >> 6;
    const int lane = tid & 63;
    const int hi = lane >> 5;
    const int l31 = lane & 31;
    const int qw0 = q0 + w * 32;
    const int diag = bx * 4 + w;
    const int nt = bx * 4 + 4;
    const size_t base_bh = (size_t)bh * (LSEQ * HD);

#pragma unroll
    for (int i = 0; i < 4; ++i) {
        int u = tid + 256 * i;
        int row = u >> 3, c = u & 7;
        int4 val = *(const int4*)(qr + base_bh + (size_t)(q0 + row) * HD + c * 8);
        *(int4*)(lds + row * 128 + ((c ^ (row & 7)) * 16)) = val;
    }

    const int st_row = tid >> 3, st_c = tid & 7;
    const int sk_off = st_row * 128 + ((st_c ^ (st_row & 7)) * 16);
    const int sv_k = tid >> 3, sv_d0 = (tid & 7) << 3;
    const int sv_kpos = (((sv_k >> 3) ^ ((sv_d0 >> 3) & 3)) * 16) + (sv_k & 7) * 2;
    const int sv_base = sv_d0 * 64 + sv_kpos;

    int4 RAk = *(const int4*)(kr + base_bh + (size_t)st_row * HD + st_c * 8);
    int4 RAv = *(const int4*)(vv + base_bh + (size_t)sv_k * HD + sv_d0);
    __syncthreads();

    bf16x8 qf[4];
    {
        const char* qrow = lds + ((w << 5) + l31) * 128;
        const int sw = l31 & 7;
#pragma unroll
        for (int ks = 0; ks < 4; ++ks) {
            int c = 2 * ks + hi;
            qf[ks] = *(const bf16x8*)(qrow + ((c ^ sw) * 16));
        }
    }
    *(int4*)(lds + 16384 + sk_off) = RAk;
    {
        union { int4 q; u16 h[8]; } uv; uv.q = RAv;
        char* vd = lds + 24576 + sv_base;
#pragma unroll
        for (int e = 0; e < 8; ++e) *(u16*)(vd + e * 64) = uv.h[e];
    }
    int4 RBk = *(const int4*)(kr + base_bh + (size_t)(32 + st_row) * HD + st_c * 8);
    int4 RBv = *(const int4*)(vv + base_bh + (size_t)(32 + sv_k) * HD + sv_d0);
    __syncthreads();

    f32x16 accO[2];
#pragma unroll
    for (int mf = 0; mf < 2; ++mf)
#pragma unroll
        for (int i = 0; i < 16; ++i) accO[mf][i] = 0.f;
    float m_run = -INFINITY, l_run = 0.f;

    const int swK = l31 & 7;
    const int rowK = l31 * 128;
    const int vr0 = l31 * 64;
    const int vsw = (l31 >> 3) & 3;

    auto compute_tile = [&](int kt, int kbase_off, int vbase_off) {
        f32x16 st;
#pragma unroll
        for (int i = 0; i < 16; ++i) st[i] = 0.f;
        const char* kb = lds + kbase_off;
#pragma unroll
        for (int ks = 0; ks < 4; ++ks) {
            int c = 2 * ks + hi;
            bf16x8 kf = *(const bf16x8*)(kb + rowK + ((c ^ swK) * 16));
            st = __builtin_amdgcn_mfma_f32_32x32x16_bf16(kf, qf[ks], st, 0, 0, 0);
        }
        const char* vb = lds + vbase_off;
        bf16x8 va00 = *(const bf16x8*)(vb + vr0 + (((0 + hi) ^ vsw) * 16));
        bf16x8 va01 = *(const bf16x8*)(vb + 2048 + vr0 + (((0 + hi) ^ vsw) * 16));
        bf16x8 va10 = *(const bf16x8*)(vb + vr0 + (((2 + hi) ^ vsw) * 16));
        bf16x8 va11 = *(const bf16x8*)(vb + 2048 + vr0 + (((2 + hi) ^ vsw) * 16));

        float s[16];
#pragma unroll
        for (int r = 0; r < 16; ++r) s[r] = st[r];
        if (kt == diag) {
            const int qg = qw0 + l31;
#pragma unroll
            for (int r = 0; r < 16; ++r) {
                int keyg = kt * 32 + (r & 3) + 8 * (r >> 2) + 4 * hi;
                if (keyg > qg) s[r] = -INFINITY;
            }
        }
        float t8[8];
#pragma unroll
        for (int r = 0; r < 8; ++r) t8[r] = fmaxf(s[r], s[r + 8]);
        float t4m[4];
#pragma unroll
        for (int r = 0; r < 4; ++r) t4m[r] = fmaxf(t8[r], t8[r + 4]);
        float mm = fmaxf(fmaxf(t4m[0], t4m[1]), fmaxf(t4m[2], t4m[3]));
        mm = fmaxf(mm, __shfl_xor(mm, 32));
        const float m_new = fmaxf(m_run, mm);
        const float sc = __expf(m_run - m_new);
        float p[16];
#pragma unroll
        for (int r = 0; r < 16; ++r) { p[r] = __expf(s[r] - m_new); }
        float a8[8];
#pragma unroll
        for (int r = 0; r < 8; ++r) a8[r] = p[r] + p[r + 8];
        float a4s[4];
#pragma unroll
        for (int r = 0; r < 4; ++r) a4s[r] = a8[r] + a8[r + 4];
        float ss = (a4s[0] + a4s[1]) + (a4s[2] + a4s[3]);
        ss += __shfl_xor(ss, 32);
        l_run = l_run * sc + ss;
        m_run = m_new;
#pragma unroll
        for (int mf = 0; mf < 2; ++mf)
#pragma unroll
            for (int i = 0; i < 16; ++i) accO[mf][i] *= sc;

        int pk[8];
#pragma unroll
        for (int i = 0; i < 8; ++i) pk[i] = cvtpkbf(p[2 * i], p[2 * i + 1]);
        int xp0 = __shfl_xor(pk[0], 32);
        int xp1 = __shfl_xor(pk[1], 32);
        int xp2 = __shfl_xor(pk[2], 32);
        int xp3 = __shfl_xor(pk[3], 32);
        int xp4 = __shfl_xor(pk[4], 32);
        int xp5 = __shfl_xor(pk[5], 32);
        int xp6 = __shfl_xor(pk[6], 32);
        int xp7 = __shfl_xor(pk[7], 32);
        const bool hib = (hi != 0);
        union { int i[4]; bf16x8 v; } pu0, pu1;
        pu0.i[0] = hib ? xp2 : pk[0];
        pu0.i[1] = hib ? xp3 : pk[1];
        pu0.i[2] = hib ? pk[2] : xp0;
        pu0.i[3] = hib ? pk[3] : xp1;
        pu1.i[0] = hib ? xp6 : pk[4];
        pu1.i[1] = hib ? xp7 : pk[5];
        pu1.i[2] = hib ? pk[6] : xp4;
        pu1.i[3] = hib ? pk[7] : xp5;

        accO[0] = __builtin_amdgcn_mfma_f32_32x32x16_bf16(va00, pu0.v, accO[0], 0, 0, 0);
        accO[1] = __builtin_amdgcn_mfma_f32_32x32x16_bf16(va01, pu0.v, accO[1], 0, 0, 0);
        accO[0] = __builtin_amdgcn_mfma_f32_32x32x16_bf16(va10, pu1.v, accO[0], 0, 0, 0);
        accO[1] = __builtin_amdgcn_mfma_f32_32x32x16_bf16(va11, pu1.v, accO[1], 0, 0, 0);
    };

    for (int kt = 0; kt < nt; kt += 2) {
        *(int4*)(lds + 16384 + 4096 + sk_off) = RBk;
        {
            union { int4 q; u16 h[8]; } uv; uv.q = RBv;
            char* vd = lds + 24576 + 4096 + sv_base;
#pragma unroll
            for (int e = 0; e < 8; ++e) *(u16*)(vd + e * 64) = uv.h[e];
        }
        if (kt + 2 < nt) {
            RAk = *(const int4*)(kr + base_bh + (size_t)((kt + 2) * 32 + st_row) * HD + st_c * 8);
            RAv = *(const int4*)(vv + base_bh + (size_t)((kt + 2) * 32 + sv_k) * HD + sv_d0);
        }
        if (kt <= diag) compute_tile(kt, 16384, 24576);
        __syncthreads();
        if (kt + 2 < nt) {
            *(int4*)(lds + 16384 + sk_off) = RAk;
            union { int4 q; u16 h[8]; } uv; uv.q = RAv;
            char* vd = lds + 24576 + sv_base;
#pragma unroll
            for (int e = 0; e < 8; ++e) *(u16*)(vd + e * 64) = uv.h[e];
        }
        if (kt + 3 < nt) {
            RBk = *(const int4*)(kr + base_bh + (size_t)((kt + 3) * 32 + st_row) * HD + st_c * 8);
            RBv = *(const int4*)(vv + base_bh + (size_t)((kt + 3) * 32 + sv_k) * HD + sv_d0);
        }
        if (kt + 1 <= diag) compute_tile(kt + 1, 16384 + 4096, 24576 + 4096);
        __syncthreads();
    }

    const float invl = 1.0f / l_run;
    const int qg = qw0 + l31;
    float* cbase = ctx + ((size_t)(bh >> 4) * LSEQ + qg) * DM + (bh & 15) * HD;
#pragma unroll
    for (int mf = 0; mf < 2; ++mf) {
#pragma unroll
        for (int g = 0; g < 4; ++g) {
            const int d4 = mf * 32 + 8 * g + 4 * hi;
            float4 c4 = *(float4*)(cbase + d4);
            c4.x += accO[mf][g * 4 + 0] * invl;
            c4.y += accO[mf][g * 4 + 1] * invl;
            c4.z += accO[mf][g * 4 + 2] * invl;
            c4.w += accO[mf][g * 4 + 3] * invl;
            *(float4*)(cbase + d4) = c4;
        }
    }
}

// ---------------------------------------------------------------------------
extern "C" void kernel_launch(void* const* d_in, const int* in_sizes, int n_in,
                              void* d_out, int out_size, void* d_ws, size_t ws_size,
                              hipStream_t stream) {
    const float* x     = (const float*)d_in[0];
    const float* wq    = (const float*)d_in[1];
    const float* wk    = (const float*)d_in[2];
    const float* wv    = (const float*)d_in[3];
    const float* wo    = (const float*)d_in[4];
    const float* gate  = (const float*)d_in[5];
    const float* decay = (const float*)d_in[6];
    const float* fcos  = (const float*)d_in[7];
    const float* fsin  = (const float*)d_in[8];
    const float* M_old = (const float*)d_in[9];
    const float* Z_old = (const float*)d_in[10];
    float* out = (float*)d_out;

    // ws layout (72 MB):
    // xb 8MB | wqb 2 | wkb 2 | wvb 2 | wob 2 | q_rope 8 | q_base 8 |
    // k_rope 8 | k_base 8 | v 8 | ctx f32 16
    u16* xb     = (u16*)d_ws;
    u16* wqb    = xb + 4194304;
    u16* wkb    = wqb + 1048576;
    u16* wvb    = wkb + 1048576;
    u16* wob    = wvb + 1048576;
    u16* q_rope = wob + 1048576;
    u16* q_base = q_rope + 4194304;
    u16* k_rope = q_base + 4194304;
    u16* k_base = k_rope + 4194304;
    u16* v      = k_base + 4194304;
    float* ctx  = (float*)(v + 4194304);
    float* lkq  = (float*)wqb;   // reuse (wq/wk dead after their GEMMs); 256KB
    float* lvq  = lkq + 65536;   // 256KB
    u16* ctxb   = xb;            // reuse (x dead after QKV GEMMs)

    dim3 bb(256);
    cvt_bf16<<<dim3(2048), bb, 0, stream>>>(x, xb, 4194304);
    cvt_bf16<<<dim3(512), bb, 0, stream>>>(wq, wqb, 1048576);
    cvt_bf16<<<dim3(512), bb, 0, stream>>>(wk, wkb, 1048576);
    cvt_bf16<<<dim3(512), bb, 0, stream>>>(wv, wvb, 1048576);
    cvt_bf16<<<dim3(512), bb, 0, stream>>>(wo, wob, 1048576);

    dim3 gg(32, 16);  // M/128 x N/64
    gemm_mfma<2><<<gg, bb, 0, stream>>>(xb, wqb, nullptr, q_base, q_rope, fcos, fsin);
    gemm_mfma<3><<<gg, bb, 0, stream>>>(xb, wkb, nullptr, k_base, k_rope, fcos, fsin);
    gemm_mfma<0><<<gg, bb, 0, stream>>>(xb, wvb, nullptr, v, nullptr, nullptr, nullptr);

    landmarks<<<dim3(NB * NH * NLM), bb, 0, stream>>>(k_base, v, lkq, lvq);
    mem_update<<<dim3(NB * NH), bb, 0, stream>>>(lkq, lvq, M_old, Z_old, decay, out);
    memory_read<<<dim3(LSEQ / 64, NB * NH), bb, 0, stream>>>(q_base, M_old, Z_old, gate, ctx);
    flash_mfma<<<dim3(LSEQ / 128, NB * NH), bb, 0, stream>>>(q_rope, k_rope, v, ctx);

    cvt_bf16<<<dim3(2048), bb, 0, stream>>>(ctx, ctxb, 4194304);
    gemm_mfma<1><<<gg, bb, 0, stream>>>(ctxb, wob, out, nullptr, nullptr, nullptr, nullptr);
}